// Round 8
// baseline (266.139 us; speedup 1.0000x reference)
//
#include <hip/hip_runtime.h>

typedef __bf16 bf16x8 __attribute__((ext_vector_type(8)));
typedef float floatx4 __attribute__((ext_vector_type(4)));

#define XS 136    // LDS row stride in bf16 elements (272 B -> 2-way bank aliasing = free)
#define ROWS 128  // rows per block

__device__ __forceinline__ unsigned short f32_bf16(float f) {
    union { float f; unsigned int u; } c; c.f = f;
    return (unsigned short)((c.u + 0x7fffu + ((c.u >> 16) & 1u)) >> 16);  // RNE, finite inputs
}

// Round-8: single kernel (prep_w1_frag eliminated -- total-dur minus moe was a
// stable ~70us across r0-r7: prep + launch gap). Routing-first row packing:
// each row is computed by ONE expert only (reference semantics), cutting MFMA
// work ~1.7-2x vs evaluate-both. Wave w = (expert e=w>>1, tile-half h=w&1)
// processes gathered m-tiles h,h+2,h+4,h+6 of its expert's packed row list
// over ALL 32 hidden-col groups (full K=512 in-wave; no slice combine).
// Weight fragments load directly from w1 (f32): per wave-load 16 rows x 128 B
// contiguous lines (coalesced-equivalent), converted inline via __bf16 cast
// (RNE v_cvt_pk, bit-identical to f32_bf16). Live VGPR ~110 fits (256,2)'s
// 128 cap (r1/r2 lesson: cap = 256/N; exceed -> catastrophic scratch spill).
__global__ __launch_bounds__(256, 2) void moe_fused(
    const float* __restrict__ x,
    const float* __restrict__ w1,             // [2][512][128] fp32
    const float* __restrict__ b1,             // [2][512]
    const float* __restrict__ w2,             // [2][2][512]
    const float* __restrict__ b2,             // [2][2]
    const float* __restrict__ protos,         // [2][128]
    float* __restrict__ out)                  // [B][2]
{
    __shared__ unsigned short xs[ROWS * XS];      // 34816 B
    __shared__ float out_s[ROWS][2];              // 1024 B
    __shared__ int   t_s[ROWS];                   // 512 B
    __shared__ unsigned short perm_s[2][ROWS];    // 512 B
    __shared__ int   c1w[2];                      // 8 B   -> ~36.9 KB

    const int tid  = threadIdx.x;
    const int lane = tid & 63;
    const int wave = tid >> 6;
    const int quad = lane >> 4;
    const int l15  = lane & 15;
    const long rowbase = (long)blockIdx.x * ROWS;

    // ---- routing: t = (d1 < d0) via sign of sum_c (p0-p1)*(0.5*(p0+p1)-x), fp64 ----
    {
        int r   = tid >> 1;                   // 2 threads per row
        int sub = tid & 1;
        const float* xr = x + (rowbase + r) * 128 + sub * 64;
        const float* p0 = protos + sub * 64;
        const float* p1 = protos + 128 + sub * 64;
        double acc = 0.0;
        #pragma unroll
        for (int k = 0; k < 16; ++k) {
            float4 xv = *(const float4*)(xr + k * 4);
            float4 a  = *(const float4*)(p0 + k * 4);
            float4 b  = *(const float4*)(p1 + k * 4);
            acc += ((double)a.x - b.x) * (0.5 * ((double)a.x + b.x) - xv.x);
            acc += ((double)a.y - b.y) * (0.5 * ((double)a.y + b.y) - xv.y);
            acc += ((double)a.z - b.z) * (0.5 * ((double)a.z + b.z) - xv.z);
            acc += ((double)a.w - b.w) * (0.5 * ((double)a.w + b.w) - xv.w);
        }
        acc += __shfl_xor(acc, 1);
        if (sub == 0) t_s[r] = (acc > 0.0) ? 1 : 0;   // tie -> expert 0 (numpy argmin)
    }

    // ---- stage x tile: coalesced float4 global reads -> bf16 LDS ----
    for (int i = tid; i < ROWS * 32; i += 256) {
        int r  = i >> 5;
        int c4 = (i & 31) * 4;
        float4 v = *(const float4*)(x + (rowbase + r) * 128 + c4);
        ushort4 p;
        p.x = f32_bf16(v.x); p.y = f32_bf16(v.y);
        p.z = f32_bf16(v.z); p.w = f32_bf16(v.w);
        *(ushort4*)&xs[r * XS + c4] = p;
    }
    __syncthreads();

    // ---- pack rows by expert: stable 2-wave ballot prefix (rows 0-63 / 64-127) ----
    unsigned long long m1 = 0;
    int myt = 0;
    if (tid < 128) {
        myt = t_s[tid];
        m1  = __ballot(myt == 1);
        if ((tid & 63) == 0) c1w[tid >> 6] = __popcll(m1);
    }
    __syncthreads();
    if (tid < 128) {
        int w  = tid >> 6;
        int ln = tid & 63;
        unsigned long long lt = (((unsigned long long)1) << ln) - 1;
        int below1 = __popcll(m1 & lt);
        int r1 = (w ? c1w[0] : 0) + below1;
        int r0 = (w ? 64 - c1w[0] : 0) + (ln - below1);
        if (myt) perm_s[1][r1] = (unsigned short)tid;
        else     perm_s[0][r0] = (unsigned short)tid;
    }
    __syncthreads();

    // ---- per-wave geometry ----
    const int e  = wave >> 1;                 // expert
    const int h  = wave & 1;                  // tile-half (even/odd m-tiles)
    const int n1 = c1w[0] + c1w[1];
    const int ne = e ? n1 : (ROWS - n1);
    const int T  = (ne + 15) >> 4;            // m-tiles for this expert (<=8)

    // gathered row addresses (halfword offset in xs) for this wave's 4 tile slots
    int raddr[4];
    #pragma unroll
    for (int i = 0; i < 4; ++i) {
        int p = (h + 2 * i) * 16 + l15;       // 0..127 always in-bounds
        raddr[i] = (perm_s[e][p] & 127) * XS; // mask guards uninit entries (p>=ne)
    }

    float outp[4][4][2] = {};   // [tile-slot][reg(row)][o] layer-2 partials

    const float* wbase = w1 + ((size_t)(e * 512 + l15 * 32)) * 128 + quad * 8;
    const float* b1p   = b1 + e * 512 + l15 * 32;
    const float* w2ap  = w2 + e * 1024 + l15 * 32;
    const float* w2bp  = w2ap + 512;

    // ---- main loop: 32 hidden-col groups; W loaded f32 + converted inline ----
    for (int ntg = 0; ntg < 32; ++ntg) {
        const float* wr = wbase + ntg * 128;  // row h=l15*32+ntg, this quad's 8 cols
        bf16x8 bw[4];
        #pragma unroll
        for (int ks = 0; ks < 4; ++ks) {
            float4 f0 = *(const float4*)(wr + ks * 32);
            float4 f1 = *(const float4*)(wr + ks * 32 + 4);
            bf16x8 t;
            t[0] = (__bf16)f0.x; t[1] = (__bf16)f0.y;
            t[2] = (__bf16)f0.z; t[3] = (__bf16)f0.w;
            t[4] = (__bf16)f1.x; t[5] = (__bf16)f1.y;
            t[6] = (__bf16)f1.z; t[7] = (__bf16)f1.w;
            bw[ks] = t;
        }
        float bb  = b1p[ntg];
        float w2a = w2ap[ntg];
        float w2b = w2bp[ntg];
        #pragma unroll
        for (int i = 0; i < 4; ++i) {
            if (h + 2 * i < T) {              // wave-uniform predicate
                floatx4 c = {bb, bb, bb, bb}; // bias folded into accumulator init
                #pragma unroll
                for (int ks = 0; ks < 4; ++ks) {
                    bf16x8 af = *(const bf16x8*)&xs[raddr[i] + ks * 32 + quad * 8];
                    c = __builtin_amdgcn_mfma_f32_16x16x32_bf16(af, bw[ks], c, 0, 0, 0);
                }
                #pragma unroll
                for (int rg = 0; rg < 4; ++rg) {
                    float hh = fmaxf(c[rg], 0.0f);
                    outp[i][rg][0] = fmaf(hh, w2a, outp[i][rg][0]);
                    outp[i][rg][1] = fmaf(hh, w2b, outp[i][rg][1]);
                }
            }
        }
    }

    // ---- reduce across the 16 column-lanes, scatter to out_s via perm ----
    #pragma unroll
    for (int i = 0; i < 4; ++i) {
        int mt = h + 2 * i;
        if (mt < T) {
            #pragma unroll
            for (int rg = 0; rg < 4; ++rg) {
                float v0 = outp[i][rg][0];
                float v1 = outp[i][rg][1];
                v0 += __shfl_xor(v0, 1);  v1 += __shfl_xor(v1, 1);
                v0 += __shfl_xor(v0, 2);  v1 += __shfl_xor(v1, 2);
                v0 += __shfl_xor(v0, 4);  v1 += __shfl_xor(v1, 4);
                v0 += __shfl_xor(v0, 8);  v1 += __shfl_xor(v1, 8);
                if (l15 == 0) {
                    int p = mt * 16 + quad * 4 + rg;  // C/D: row = quad*4 + reg
                    if (p < ne) {
                        int r = perm_s[e][p];
                        out_s[r][0] = v0;
                        out_s[r][1] = v1;
                    }
                }
            }
        }
    }
    __syncthreads();

    // ---- add b2, coalesced store (each row written by exactly one expert) ----
    {
        int r  = tid >> 1;
        int o  = tid & 1;
        int te = t_s[r];
        out[(rowbase + r) * 2 + o] = out_s[r][o] + b2[te * 2 + o];
    }
}

extern "C" void kernel_launch(void* const* d_in, const int* in_sizes, int n_in,
                              void* d_out, int out_size, void* d_ws, size_t ws_size,
                              hipStream_t stream) {
    const float* x      = (const float*)d_in[0];
    const float* w1     = (const float*)d_in[1];
    const float* b1     = (const float*)d_in[2];
    const float* w2     = (const float*)d_in[3];
    const float* b2     = (const float*)d_in[4];
    const float* protos = (const float*)d_in[5];
    float* out = (float*)d_out;
    (void)d_ws; (void)ws_size;

    moe_fused<<<dim3(1024), dim3(256), 0, stream>>>(x, w1, b1, w2, b2, protos, out);
}

// Round 9
// 165.397 us; speedup vs baseline: 1.6091x; 1.6091x over previous
//
#include <hip/hip_runtime.h>

typedef __bf16 bf16x8 __attribute__((ext_vector_type(8)));
typedef float floatx4 __attribute__((ext_vector_type(4)));

#define XS 136      // LDS row stride in bf16 elements (272 B -> 2-way bank aliasing = free)
#define ROWS 128    // rows per block
#define PADROWS 144 // packed+tile-padded row slots (max ceil(n0/16)*16 + ceil(n1/16)*16)

__device__ __forceinline__ unsigned short f32_bf16(float f) {
    union { float f; unsigned int u; } c; c.f = f;
    return (unsigned short)((c.u + 0x7fffu + ((c.u >> 16) & 1u)) >> 16);  // RNE, finite inputs
}

// w1 -> MFMA B-fragment order, hidden-col mapping h(nt,l15) = l15*32 + nt.
// frag f = (e*32+nt)*4+ks ; lane (quad,l15) holds B[k=quad*8+j][n=l15] = w1[e][h][k]
__global__ __launch_bounds__(256) void prep_w1_frag(const float* __restrict__ w1,
                                                    unsigned short* __restrict__ wbf) {
    int g    = blockIdx.x * 256 + threadIdx.x;   // 64 blocks -> 16384 threads
    int lane = g & 63;
    int frag = g >> 6;                            // 0..255
    int ks   = frag & 3;
    int nt   = (frag >> 2) & 31;
    int e    = frag >> 7;
    int l15  = lane & 15;
    int quad = lane >> 4;
    int h    = l15 * 32 + nt;
    const float* src = w1 + ((e * 512 + h) * 128 + ks * 32 + quad * 8);
    unsigned short* dst = wbf + (long)g * 8;      // 16 B/lane, contiguous per wave
    #pragma unroll
    for (int j = 0; j < 8; ++j) dst[j] = f32_bf16(src[j]);
}

// Round-9: r0's proven 90us structure + routing-first row packing, with the
// permutation applied AT STAGING (write side) so all MFMA-side LDS reads are
// consecutive-row (r0's conflict-free pattern; r8's gathered reads caused the
// 6.2M-conflict blowup). Expert-0 rows pack to slots [0,n0); expert-1 to
// [P, P+n1), P = ceil(n0/16)*16; pad slots zero-filled (their outputs are
// discarded). Main loop = r0 body + wave-uniform `if (mt < Te)` guard ->
// per-block tile-slices drop 16 -> ~9.8 avg (1.63x cut of dominant phase).
// Weights from fragment-ordered wbf (prep is free; total-dur gap ~70us is
// fixed harness overhead, measured with 1 kernel in r8).
__global__ __launch_bounds__(256, 2) void moe_fused(
    const float* __restrict__ x,
    const unsigned short* __restrict__ wbf,   // fragment-ordered bf16 w1
    const float* __restrict__ b1,             // [2][512]
    const float* __restrict__ w2,             // [2][2][512]
    const float* __restrict__ b2,             // [2][2]
    const float* __restrict__ protos,         // [2][128]
    float* __restrict__ out)                  // [B][2]
{
    __shared__ unsigned short xs[PADROWS * XS];   // 39168 B (packed bf16 rows)
    __shared__ float out_s[2][ROWS][2];           // [slice][row][o] 2048 B
    __shared__ int   t_s[ROWS];                   // 512 B
    __shared__ unsigned short perm_s[2][ROWS];    // packed idx -> source row, 512 B
    __shared__ int   c1w[2];                      // per-wave expert-1 counts, 8 B

    const int tid   = threadIdx.x;
    const int lane  = tid & 63;
    const int wave  = tid >> 6;
    const int quad  = lane >> 4;
    const int l15   = lane & 15;
    const int slice = wave & 1;               // nt-half 0/1
    const int e     = wave >> 1;              // expert
    const long rowbase = (long)blockIdx.x * ROWS;

    // ---- routing: t = (d1 < d0) via sign of sum_c (p0-p1)*(0.5*(p0+p1)-x), fp64 ----
    {
        int r   = tid >> 1;                   // 2 threads per row
        int sub = tid & 1;
        const float* xr = x + (rowbase + r) * 128 + sub * 64;
        const float* p0 = protos + sub * 64;
        const float* p1 = protos + 128 + sub * 64;
        double acc = 0.0;
        #pragma unroll
        for (int k = 0; k < 16; ++k) {
            float4 xv = *(const float4*)(xr + k * 4);
            float4 a  = *(const float4*)(p0 + k * 4);
            float4 b  = *(const float4*)(p1 + k * 4);
            acc += ((double)a.x - b.x) * (0.5 * ((double)a.x + b.x) - xv.x);
            acc += ((double)a.y - b.y) * (0.5 * ((double)a.y + b.y) - xv.y);
            acc += ((double)a.z - b.z) * (0.5 * ((double)a.z + b.z) - xv.z);
            acc += ((double)a.w - b.w) * (0.5 * ((double)a.w + b.w) - xv.w);
        }
        acc += __shfl_xor(acc, 1);
        if (sub == 0) t_s[r] = (acc > 0.0) ? 1 : 0;   // tie -> expert 0 (numpy argmin)
    }
    __syncthreads();

    // ---- pack rows by expert: stable 2-wave ballot prefix (rows 0-63 / 64-127) ----
    unsigned long long m1 = 0;
    int myt = 0;
    if (tid < 128) {
        myt = t_s[tid];
        m1  = __ballot(myt == 1);
        if ((tid & 63) == 0) c1w[tid >> 6] = __popcll(m1);
    }
    __syncthreads();
    if (tid < 128) {
        int w  = tid >> 6;
        int ln = tid & 63;
        unsigned long long lt = (((unsigned long long)1) << ln) - 1;
        int below1 = __popcll(m1 & lt);
        int r1 = (w ? c1w[0] : 0) + below1;
        int r0 = (w ? 64 - c1w[0] : 0) + (ln - below1);
        if (myt) perm_s[1][r1] = (unsigned short)tid;
        else     perm_s[0][r0] = (unsigned short)tid;
    }
    __syncthreads();

    const int n1 = c1w[0] + c1w[1];
    const int n0 = ROWS - n1;
    const int P  = (n0 + 15) & ~15;           // expert-1 packed base (tile-aligned)

    // ---- stage x PERMUTED by destination slot: coalesced 128B-per-rowgroup reads ----
    // slot p < n0 : source row perm_s[0][p] ; P <= p < P+n1 : perm_s[1][p-P] ; else 0
    for (int i = tid; i < PADROWS * 32; i += 256) {
        int p  = i >> 5;
        int c4 = (i & 31) * 4;
        ushort4 pk = {0, 0, 0, 0};
        int src = -1;
        if (p < n0)                    src = perm_s[0][p];
        else if (p >= P && p - P < n1) src = perm_s[1][p - P];
        if (src >= 0) {
            float4 v = *(const float4*)(x + (rowbase + src) * 128 + c4);
            pk.x = f32_bf16(v.x); pk.y = f32_bf16(v.y);
            pk.z = f32_bf16(v.z); pk.w = f32_bf16(v.w);
        }
        *(ushort4*)&xs[p * XS + c4] = pk;
    }
    __syncthreads();

    // ---- per-wave geometry: this expert's packed tiles ----
    const int ne    = e ? n1 : n0;
    const int Te    = __builtin_amdgcn_readfirstlane((ne + 15) >> 4);  // <= 8, scalar
    const int pbase = e ? P : 0;

    // ---- A fragments: up to 8 packed m-tiles x 4 k-steps (guarded pre-read) ----
    // A-operand layout: A[m = lane&15][k = quad*8 + j]
    bf16x8 afrag[8][4];
    #pragma unroll
    for (int mt = 0; mt < 8; ++mt) {
        if (mt < Te) {
            int r = pbase + mt * 16 + l15;
            #pragma unroll
            for (int ks = 0; ks < 4; ++ks)
                afrag[mt][ks] = *(const bf16x8*)&xs[r * XS + ks * 32 + quad * 8];
        }
    }

    float outp[8][4][2] = {};   // [m-tile][reg(row)][o] layer-2 partials

    // ---- main loop: 16 n-tiles (this wave's expert + nt-half), r0 body + guard ----
    const bf16x8* wb8 = (const bf16x8*)wbf + (long)((e * 32 + slice * 16) * 4) * 64 + lane;
    const int    coff = e * 512 + l15 * 32 + slice * 16;
    const float* b1p  = b1 + coff;
    const float* w2ap = w2 + e * 1024 + l15 * 32 + slice * 16;
    const float* w2bp = w2ap + 512;
    for (int nt = 0; nt < 16; ++nt) {
        const bf16x8* wp = wb8 + nt * 256;
        bf16x8 bf0 = wp[0];
        bf16x8 bf1 = wp[64];
        bf16x8 bf2 = wp[128];
        bf16x8 bf3 = wp[192];
        float bb  = b1p[nt];
        float w2a = w2ap[nt];
        float w2b = w2bp[nt];
        #pragma unroll
        for (int mt = 0; mt < 8; ++mt) {
            if (mt < Te) {                    // wave-uniform scalar predicate
                floatx4 c = {bb, bb, bb, bb}; // bias folded into accumulator init
                c = __builtin_amdgcn_mfma_f32_16x16x32_bf16(afrag[mt][0], bf0, c, 0, 0, 0);
                c = __builtin_amdgcn_mfma_f32_16x16x32_bf16(afrag[mt][1], bf1, c, 0, 0, 0);
                c = __builtin_amdgcn_mfma_f32_16x16x32_bf16(afrag[mt][2], bf2, c, 0, 0, 0);
                c = __builtin_amdgcn_mfma_f32_16x16x32_bf16(afrag[mt][3], bf3, c, 0, 0, 0);
                #pragma unroll
                for (int rg = 0; rg < 4; ++rg) {
                    float h = fmaxf(c[rg], 0.0f);
                    outp[mt][rg][0] = fmaf(h, w2a, outp[mt][rg][0]);
                    outp[mt][rg][1] = fmaf(h, w2b, outp[mt][rg][1]);
                }
            }
        }
    }

    // ---- reduce layer-2 partials across 16 column-lanes, scatter via perm ----
    #pragma unroll
    for (int mt = 0; mt < 8; ++mt) {
        if (mt < Te) {
            #pragma unroll
            for (int rg = 0; rg < 4; ++rg) {
                float v0 = outp[mt][rg][0];
                float v1 = outp[mt][rg][1];
                v0 += __shfl_xor(v0, 1);  v1 += __shfl_xor(v1, 1);
                v0 += __shfl_xor(v0, 2);  v1 += __shfl_xor(v1, 2);
                v0 += __shfl_xor(v0, 4);  v1 += __shfl_xor(v1, 4);
                v0 += __shfl_xor(v0, 8);  v1 += __shfl_xor(v1, 8);
                if (l15 == 0) {
                    int p = mt * 16 + quad * 4 + rg;  // C/D: row = quad*4 + reg
                    if (p < ne) {
                        int r = perm_s[e][p];
                        out_s[slice][r][0] = v0;
                        out_s[slice][r][1] = v1;
                    }
                }
            }
        }
    }
    __syncthreads();

    // ---- combine nt-halves, add b2, coalesced store (each row in exactly 1 list) ----
    {
        int r  = tid >> 1;
        int o  = tid & 1;
        int te = t_s[r];
        out[(rowbase + r) * 2 + o] =
            out_s[0][r][o] + out_s[1][r][o] + b2[te * 2 + o];
    }
}

extern "C" void kernel_launch(void* const* d_in, const int* in_sizes, int n_in,
                              void* d_out, int out_size, void* d_ws, size_t ws_size,
                              hipStream_t stream) {
    const float* x      = (const float*)d_in[0];
    const float* w1     = (const float*)d_in[1];
    const float* b1     = (const float*)d_in[2];
    const float* w2     = (const float*)d_in[3];
    const float* b2     = (const float*)d_in[4];
    const float* protos = (const float*)d_in[5];
    float* out = (float*)d_out;
    unsigned short* wbf = (unsigned short*)d_ws;   // 256 KiB bf16 fragment-ordered w1

    prep_w1_frag<<<dim3(64), dim3(256), 0, stream>>>(w1, wbf);
    moe_fused<<<dim3(1024), dim3(256), 0, stream>>>(x, wbf, b1, w2, b2, protos, out);
}